// Round 13
// baseline (1655.779 us; speedup 1.0000x reference)
//
#include <hip/hip_runtime.h>
#include <float.h>

// Chamfer L2, B=4, N=M=8192 fp32 -> scalar.
// bf16 MFMA, K-packed (K=16), symmetric score s_ij = -0.5 d_ij:
//   row-max -> d1 (p1->p2), col-max -> d2 (p2->p1), one MFMA serves both.
// R13: fully-unrolled 32-tile loop, 1 tile/iter (2 MFMAs, transient accs);
// col partials in REGISTERS (colA/colB f32x16, static tile index) --
// cross-half shfl + LDS atomicMin hoisted out of the loop (once per wave,
// was per tile in R12). launch_bounds(256,3) ~170-reg cap, ~135 est usage.
// C layout (HW-verified): col=lane&31, row=(reg&3)+8*(reg>>2)+4*(lane>>5).
// Note: harness re-poison of ws (~41us fill @ 268MB) is a fixed cost in the
// timed region; only the kernel pipeline after it is ours to optimize.

typedef short sh8    __attribute__((ext_vector_type(8)));
typedef float f32x16 __attribute__((ext_vector_type(16)));

#define BLK   256
#define BATCH 4
#define NPTS  8192
#define PCH   8                      // point (col) chunks
#define PCHUNK (NPTS / PCH)          // 1024 points staged (32 KB LDS)
#define QA    2                      // A fragments per wave
#define QPW   (QA * 32)              // 64 rows per wave
#define QPB   (4 * QPW)              // 256 rows per block
#define QTILES (NPTS / QPB)          // 32
#define GRID  (BATCH * QTILES * PCH)      // 1024
#define NROW  (BATCH * NPTS)              // 32768
#define WS_NEED ((size_t)(PCH + QTILES) * NROW * sizeof(float))  // 5.25 MB
#define ONEBF 0x3F80
#define NEGMAXU 0xFF7FFFFFu          // bits of -FLT_MAX

__device__ __forceinline__ short f2bf(float f) {
    unsigned u = __float_as_uint(f);
    unsigned r = (u + 0x7FFFu + ((u >> 16) & 1u)) >> 16;
    return (short)r;
}
__device__ __forceinline__ float bf2f(short h) {
    return __uint_as_float(((unsigned)(unsigned short)h) << 16);
}
__device__ __forceinline__ float tree_max16(f32x16 v) {
    float a = fmaxf(fmaxf(v[0], v[1]), v[2]);
    float b = fmaxf(fmaxf(v[3], v[4]), v[5]);
    float c = fmaxf(fmaxf(v[6], v[7]), v[8]);
    float d = fmaxf(fmaxf(v[9], v[10]), v[11]);
    float e = fmaxf(fmaxf(v[12], v[13]), v[14]);
    float f = fmaxf(fmaxf(a, b), c);
    float g = fmaxf(fmaxf(d, e), v[15]);
    return fmaxf(f, g);
}

__global__ void zero_out_kernel(float* out) { out[0] = 0.f; }

__global__ __launch_bounds__(BLK, 3) void cd_mfma_kernel(
    const float* __restrict__ p1, const float* __restrict__ p2,
    float* __restrict__ part1, float* __restrict__ part2)
{
    __shared__ uint4 ptsB[2 * PCHUNK];     // [half][point], 32 KB
    __shared__ unsigned colbuf[PCHUNK];    // col-max bits, 4 KB

    int bid    = blockIdx.x;
    int pchunk = bid & (PCH - 1);
    int qt     = (bid >> 3) & (QTILES - 1);
    int batch  = bid >> 8;

    const float* qbase = p1 + (size_t)batch * NPTS * 3;   // rows
    const float* dbase = p2 + (size_t)batch * NPTS * 3;   // cols

    int tid  = threadIdx.x;
    int wave = tid >> 6;
    int lane = tid & 63;
    int col  = lane & 31;
    int half = lane >> 5;

    // ---- stage 1024 p2 points + init colbuf ----
    #pragma unroll
    for (int it = 0; it < PCHUNK / BLK; ++it) {
        int p = tid + it * BLK;
        colbuf[p] = NEGMAXU;
        const float* s = dbase + (size_t)(pchunk * PCHUNK + p) * 3;
        float x = s[0], y = s[1], z = s[2];
        short hx = f2bf(x), hy = f2bf(y), hz = f2bf(z);
        short lx = f2bf(x - bf2f(hx));
        short ly = f2bf(y - bf2f(hy));
        short lz = f2bf(z - bf2f(hz));
        float w = -0.5f * (x * x + y * y + z * z);
        short wh = f2bf(w);
        short wl = f2bf(w - bf2f(wh));
        unsigned uhx = (unsigned short)hx, uhy = (unsigned short)hy, uhz = (unsigned short)hz;
        unsigned ulx = (unsigned short)lx, uly = (unsigned short)ly, ulz = (unsigned short)lz;
        // half0 k0-7: [phx phy phz phx phy phz plx ply]
        ptsB[p] = make_uint4(uhx | (uhy << 16), uhz | (uhx << 16),
                             uhy | (uhz << 16), ulx | (uly << 16));
        // half1 k8-15: [plz plx ply plz wh wl 1 1]
        ptsB[PCHUNK + p] = make_uint4(
            ulz | (ulx << 16), uly | (ulz << 16),
            (unsigned)(unsigned short)wh | ((unsigned)(unsigned short)wl << 16),
            ((unsigned)ONEBF) | (((unsigned)ONEBF) << 16));
    }

    // ---- A fragments: QA row groups of 32 per wave (p1 queries) ----
    sh8 afrag[QA];
    #pragma unroll
    for (int qa = 0; qa < QA; ++qa) {
        int q = qt * QPB + wave * QPW + qa * 32 + col;
        const float* s = qbase + (size_t)q * 3;
        float x = s[0], y = s[1], z = s[2];
        short hx = f2bf(x), hy = f2bf(y), hz = f2bf(z);
        short lx = f2bf(x - bf2f(hx));
        short ly = f2bf(y - bf2f(hy));
        short lz = f2bf(z - bf2f(hz));
        float w = -0.5f * (x * x + y * y + z * z);
        short nh = f2bf(w);
        short nl = f2bf(w - bf2f(nh));
        // half0 k0-7: [qhx qhy qhz qlx qly qlz qhx qhy]
        // half1 k8-15:[qhz qlx qly qlz  1   1  qnh qnl]
        afrag[qa][0] = half ? hz : hx;
        afrag[qa][1] = half ? lx : hy;
        afrag[qa][2] = half ? ly : hz;
        afrag[qa][3] = half ? lz : lx;
        afrag[qa][4] = half ? (short)ONEBF : ly;
        afrag[qa][5] = half ? (short)ONEBF : lz;
        afrag[qa][6] = half ? nh : hx;
        afrag[qa][7] = half ? nl : hy;
    }
    __syncthreads();

    f32x16 zc;
    f32x16 runmax0, runmax1, colA, colB;
    #pragma unroll
    for (int i = 0; i < 16; ++i) {
        zc[i] = 0.f;
        runmax0[i] = -FLT_MAX;
        runmax1[i] = -FLT_MAX;
    }

    const uint4* bbase = ptsB + half * PCHUNK + col;

    // ---- fully-unrolled 32 tiles, 1 tile/iter ----
    #pragma unroll
    for (int t = 0; t < PCHUNK / 32; ++t) {
        sh8 b = *(const sh8*)(bbase + t * 32);
        f32x16 a0 = __builtin_amdgcn_mfma_f32_32x32x16_bf16(afrag[0], b, zc, 0, 0, 0);
        f32x16 a1 = __builtin_amdgcn_mfma_f32_32x32x16_bf16(afrag[1], b, zc, 0, 0, 0);
        runmax0 = __builtin_elementwise_max(runmax0, a0);
        runmax1 = __builtin_elementwise_max(runmax1, a1);
        f32x16 c = __builtin_elementwise_max(a0, a1);
        float m = tree_max16(c);
        if (t < 16) colA[t] = m; else colB[t - 16] = m;
    }

    // ---- row epilogue: shfl-reduce over 32 col-lanes -> part1 ----
    int row0 = batch * NPTS + qt * QPB + wave * QPW;
    float* prow = part1 + (size_t)pchunk * NROW + row0;
    {
        f32x16 rm = runmax0;
        #pragma unroll
        for (int step = 1; step <= 16; step <<= 1) {
            f32x16 o;
            #pragma unroll
            for (int i = 0; i < 16; ++i) o[i] = __shfl_xor(rm[i], step, 64);
            rm = __builtin_elementwise_max(rm, o);
        }
        if (col == 0) {
            #pragma unroll
            for (int reg = 0; reg < 16; ++reg) {
                int r = (reg & 3) + 8 * (reg >> 2) + 4 * half;
                prow[r] = fmaxf(-2.f * rm[reg], 0.f);
            }
        }
        rm = runmax1;
        #pragma unroll
        for (int step = 1; step <= 16; step <<= 1) {
            f32x16 o;
            #pragma unroll
            for (int i = 0; i < 16; ++i) o[i] = __shfl_xor(rm[i], step, 64);
            rm = __builtin_elementwise_max(rm, o);
        }
        if (col == 0) {
            #pragma unroll
            for (int reg = 0; reg < 16; ++reg) {
                int r = (reg & 3) + 8 * (reg >> 2) + 4 * half;
                prow[32 + r] = fmaxf(-2.f * rm[reg], 0.f);
            }
        }
    }

    // ---- col epilogue: combine halves once, then 32 LDS atomics/wave ----
    #pragma unroll
    for (int j = 0; j < 16; ++j) {
        colA[j] = fmaxf(colA[j], __shfl_xor(colA[j], 32, 64));
        colB[j] = fmaxf(colB[j], __shfl_xor(colB[j], 32, 64));
    }
    if (half == 0) {
        #pragma unroll
        for (int j = 0; j < 16; ++j) {
            atomicMin(&colbuf[j * 32 + col], __float_as_uint(colA[j]));
            atomicMin(&colbuf[(16 + j) * 32 + col], __float_as_uint(colB[j]));
        }
    }
    __syncthreads();
    float* pcol = part2 + (size_t)qt * NROW + batch * NPTS + pchunk * PCHUNK;
    #pragma unroll
    for (int it = 0; it < PCHUNK / BLK; ++it) {
        int c = tid + it * BLK;
        float s = __uint_as_float(colbuf[c]);
        pcol[c] = fmaxf(-2.f * s, 0.f);
    }
}

// Stage 2: per row/col min over partials, block-sum -> atomicAdd out.
__global__ __launch_bounds__(BLK) void min_sum_kernel(
    const float* __restrict__ part, float* __restrict__ out,
    int nparts, float scale)
{
    int qid = blockIdx.x * BLK + threadIdx.x;
    float v = FLT_MAX;
    for (int m = 0; m < nparts; ++m)
        v = fminf(v, part[(size_t)m * NROW + qid]);
    for (int off = 32; off > 0; off >>= 1) v += __shfl_down(v, off, 64);
    __shared__ float wsum[BLK / 64];
    int lane = threadIdx.x & 63, wid = threadIdx.x >> 6;
    if (lane == 0) wsum[wid] = v;
    __syncthreads();
    if (threadIdx.x == 0) {
        float t = 0.f;
        for (int w = 0; w < BLK / 64; ++w) t += wsum[w];
        atomicAdd(out, t * scale);
    }
}

// ---- fallback path (ws too small): fp32 VALU + atomicMin ----
typedef float v2f __attribute__((ext_vector_type(2)));
typedef float v4f __attribute__((ext_vector_type(4)));
#define FQPT   8
#define FNCH   32
#define FCHUNK (NPTS / FNCH)
#define TOTQ  (2 * BATCH * NPTS)

__global__ __launch_bounds__(BLK) void init_kernel(unsigned* mins, float* out, int n) {
    int i = blockIdx.x * BLK + threadIdx.x;
    if (i < n) mins[i] = 0x7F7FFFFFu;
    if (i == 0) out[0] = 0.f;
}

__global__ __launch_bounds__(BLK) void cd_chunk_atomic_kernel(
    const float* __restrict__ p1, const float* __restrict__ p2,
    unsigned* __restrict__ mins)
{
    __shared__ v4f pts[FCHUNK];
    int bid    = blockIdx.x;
    int mchunk = bid & (FNCH - 1);
    int qt     = (bid >> 5) & 3;
    int batch  = (bid >> 7) & (BATCH - 1);
    int dir    = bid >> 9;
    const float* qbase = (dir == 0 ? p1 : p2) + (size_t)batch * NPTS * 3;
    const float* dbase = (dir == 0 ? p2 : p1) + (size_t)batch * NPTS * 3;
    int tid = threadIdx.x;
    if (tid < FCHUNK / 4) {
        int t4 = tid * 4;
        const float* s = dbase + (size_t)(mchunk * FCHUNK + t4) * 3;
        float4 f0 = *(const float4*)(s);
        float4 f1 = *(const float4*)(s + 4);
        float4 f2 = *(const float4*)(s + 8);
        float x0 = f0.x, y0 = f0.y, z0 = f0.z;
        float x1 = f0.w, y1 = f1.x, z1 = f1.y;
        float x2 = f1.z, y2 = f1.w, z2 = f2.x;
        float x3 = f2.y, y3 = f2.z, z3 = f2.w;
        float w0 = -0.5f * (x0*x0 + y0*y0 + z0*z0);
        float w1 = -0.5f * (x1*x1 + y1*y1 + z1*z1);
        float w2 = -0.5f * (x2*x2 + y2*y2 + z2*z2);
        float w3 = -0.5f * (x3*x3 + y3*y3 + z3*z3);
        pts[4*tid + 0] = (v4f){x0, x1, y0, y1};
        pts[4*tid + 1] = (v4f){z0, z1, w0, w1};
        pts[4*tid + 2] = (v4f){x2, x3, y2, y3};
        pts[4*tid + 3] = (v4f){z2, z3, w2, w3};
    }
    v2f qx2[FQPT], qy2[FQPT], qz2[FQPT];
    float qn[FQPT];
    #pragma unroll
    for (int k = 0; k < FQPT; ++k) {
        int q = qt * (BLK * FQPT) + k * BLK + tid;
        const float* s = qbase + (size_t)q * 3;
        float qx = s[0], qy = s[1], qz = s[2];
        qx2[k] = (v2f){qx, qx}; qy2[k] = (v2f){qy, qy}; qz2[k] = (v2f){qz, qz};
        qn[k] = qx * qx + qy * qy + qz * qz;
    }
    __syncthreads();
    v2f acc0[FQPT], acc1[FQPT];
    #pragma unroll
    for (int k = 0; k < FQPT; ++k) {
        acc0[k] = (v2f){-FLT_MAX, -FLT_MAX};
        acc1[k] = (v2f){-FLT_MAX, -FLT_MAX};
    }
    #pragma unroll 2
    for (int m = 0; m < FCHUNK / 2; m += 2) {
        v4f u0 = pts[2*m + 0], v0 = pts[2*m + 1];
        v4f u1 = pts[2*m + 2], v1 = pts[2*m + 3];
        v2f X0 = __builtin_shufflevector(u0, u0, 0, 1);
        v2f Y0 = __builtin_shufflevector(u0, u0, 2, 3);
        v2f Z0 = __builtin_shufflevector(v0, v0, 0, 1);
        v2f W0 = __builtin_shufflevector(v0, v0, 2, 3);
        v2f X1 = __builtin_shufflevector(u1, u1, 0, 1);
        v2f Y1 = __builtin_shufflevector(u1, u1, 2, 3);
        v2f Z1 = __builtin_shufflevector(v1, v1, 0, 1);
        v2f W1 = __builtin_shufflevector(v1, v1, 2, 3);
        #pragma unroll
        for (int k = 0; k < FQPT; ++k) {
            v2f s0 = __builtin_elementwise_fma(qz2[k], Z0,
                      __builtin_elementwise_fma(qy2[k], Y0,
                       __builtin_elementwise_fma(qx2[k], X0, W0)));
            acc0[k] = __builtin_elementwise_max(acc0[k], s0);
            v2f s1 = __builtin_elementwise_fma(qz2[k], Z1,
                      __builtin_elementwise_fma(qy2[k], Y1,
                       __builtin_elementwise_fma(qx2[k], X1, W1)));
            acc1[k] = __builtin_elementwise_max(acc1[k], s1);
        }
    }
    unsigned qid = (unsigned)(dir * (BATCH * NPTS) + batch * NPTS + qt * (BLK * FQPT) + tid);
    #pragma unroll
    for (int k = 0; k < FQPT; ++k) {
        float mx = fmaxf(fmaxf(acc0[k].x, acc0[k].y), fmaxf(acc1[k].x, acc1[k].y));
        float d = fmaxf(qn[k] - 2.f * mx, 0.f);
        atomicMin(&mins[qid + k * BLK], __float_as_uint(d));
    }
}

__global__ __launch_bounds__(BLK) void sum_kernel(
    const unsigned* __restrict__ mins, float* __restrict__ out, int n, float scale)
{
    int i = blockIdx.x * BLK + threadIdx.x;
    int stride = gridDim.x * BLK;
    float v = 0.f;
    for (int idx = i; idx < n; idx += stride) v += __uint_as_float(mins[idx]);
    for (int off = 32; off > 0; off >>= 1) v += __shfl_down(v, off, 64);
    __shared__ float wsum[BLK / 64];
    int lane = threadIdx.x & 63, wid = threadIdx.x >> 6;
    if (lane == 0) wsum[wid] = v;
    __syncthreads();
    if (threadIdx.x == 0) {
        float t = 0.f;
        for (int w = 0; w < BLK / 64; ++w) t += wsum[w];
        atomicAdd(out, t * scale);
    }
}

extern "C" void kernel_launch(void* const* d_in, const int* in_sizes, int n_in,
                              void* d_out, int out_size, void* d_ws, size_t ws_size,
                              hipStream_t stream) {
    const float* p1 = (const float*)d_in[0];
    const float* p2 = (const float*)d_in[1];
    float* out = (float*)d_out;

    if (ws_size >= WS_NEED) {
        float* part1 = (float*)d_ws;                       // PCH x NROW (1 MB)
        float* part2 = part1 + (size_t)PCH * NROW;         // QTILES x NROW (4 MB)
        zero_out_kernel<<<1, 1, 0, stream>>>(out);
        cd_mfma_kernel<<<GRID, BLK, 0, stream>>>(p1, p2, part1, part2);
        min_sum_kernel<<<NROW / BLK, BLK, 0, stream>>>(part1, out, PCH,
                                                       1.f / (float)NROW);
        min_sum_kernel<<<NROW / BLK, BLK, 0, stream>>>(part2, out, QTILES,
                                                       1.f / (float)NROW);
    } else {
        unsigned* mins = (unsigned*)d_ws;
        init_kernel<<<TOTQ / BLK, BLK, 0, stream>>>(mins, out, TOTQ);
        cd_chunk_atomic_kernel<<<1024, BLK, 0, stream>>>(p1, p2, mins);
        sum_kernel<<<64, BLK, 0, stream>>>(mins, out, TOTQ, 1.f / (float)(BATCH * NPTS));
    }
}

// Round 14
// 91.458 us; speedup vs baseline: 18.1042x; 18.1042x over previous
//
#include <hip/hip_runtime.h>
#include <float.h>

// Chamfer L2, B=4, N=M=8192 fp32 -> scalar.
// bf16 MFMA, K-packed (K=16), symmetric score s_ij = -0.5 d_ij:
//   row-max -> d1 (p1->p2), col-max -> d2 (p2->p1), one MFMA serves both.
// R14 = R12 (known-good) + joint 32-elem max3 col tree + fused stage-2.
// R13 LESSON: never variable-index an ext_vector (colA[t]) -- LLVM demotes
// to scratch alloca before unroll; caused 5.7GB/dispatch scratch thrash.
// C layout (HW-verified): col=lane&31, row=(reg&3)+8*(reg>>2)+4*(lane>>5).

typedef short sh8    __attribute__((ext_vector_type(8)));
typedef float f32x16 __attribute__((ext_vector_type(16)));

#define BLK   256
#define BATCH 4
#define NPTS  8192
#define PCH   8                      // point (col) chunks
#define PCHUNK (NPTS / PCH)          // 1024 points staged (32 KB LDS)
#define QA    2                      // A fragments per wave
#define QPW   (QA * 32)              // 64 rows per wave
#define QPB   (4 * QPW)              // 256 rows per block
#define QTILES (NPTS / QPB)          // 32
#define GRID  (BATCH * QTILES * PCH)      // 1024
#define NROW  (BATCH * NPTS)              // 32768
#define WS_NEED ((size_t)(PCH + QTILES) * NROW * sizeof(float))  // 5.25 MB
#define ONEBF 0x3F80
#define NEGMAXU 0xFF7FFFFFu          // bits of -FLT_MAX

__device__ __forceinline__ short f2bf(float f) {
    unsigned u = __float_as_uint(f);
    unsigned r = (u + 0x7FFFu + ((u >> 16) & 1u)) >> 16;
    return (short)r;
}
__device__ __forceinline__ float bf2f(short h) {
    return __uint_as_float(((unsigned)(unsigned short)h) << 16);
}
// max over two f32x16 (32 values) in max3-friendly groups (~18 instrs)
__device__ __forceinline__ float tree_max32(f32x16 u, f32x16 v) {
    float a0 = fmaxf(fmaxf(u[0], u[1]), u[2]);
    float a1 = fmaxf(fmaxf(u[3], u[4]), u[5]);
    float a2 = fmaxf(fmaxf(u[6], u[7]), u[8]);
    float a3 = fmaxf(fmaxf(u[9], u[10]), u[11]);
    float a4 = fmaxf(fmaxf(u[12], u[13]), u[14]);
    float a5 = fmaxf(fmaxf(u[15], v[0]), v[1]);
    float a6 = fmaxf(fmaxf(v[2], v[3]), v[4]);
    float a7 = fmaxf(fmaxf(v[5], v[6]), v[7]);
    float a8 = fmaxf(fmaxf(v[8], v[9]), v[10]);
    float a9 = fmaxf(fmaxf(v[11], v[12]), v[13]);
    float aA = fmaxf(v[14], v[15]);
    float b0 = fmaxf(fmaxf(a0, a1), a2);
    float b1 = fmaxf(fmaxf(a3, a4), a5);
    float b2 = fmaxf(fmaxf(a6, a7), a8);
    float b3 = fmaxf(a9, aA);
    return fmaxf(fmaxf(b0, b1), fmaxf(b2, b3));
}

__global__ void zero_out_kernel(float* out) { out[0] = 0.f; }

__global__ __launch_bounds__(BLK, 2) void cd_mfma_kernel(
    const float* __restrict__ p1, const float* __restrict__ p2,
    float* __restrict__ part1, float* __restrict__ part2)
{
    __shared__ uint4 ptsB[2 * PCHUNK];     // [half][point], 32 KB
    __shared__ unsigned colbuf[PCHUNK];    // col-max bits, 4 KB

    int bid    = blockIdx.x;
    int pchunk = bid & (PCH - 1);
    int qt     = (bid >> 3) & (QTILES - 1);
    int batch  = bid >> 8;

    const float* qbase = p1 + (size_t)batch * NPTS * 3;   // rows
    const float* dbase = p2 + (size_t)batch * NPTS * 3;   // cols

    int tid  = threadIdx.x;
    int wave = tid >> 6;
    int lane = tid & 63;
    int col  = lane & 31;
    int half = lane >> 5;

    // ---- stage 1024 p2 points + init colbuf ----
    #pragma unroll
    for (int it = 0; it < PCHUNK / BLK; ++it) {
        int p = tid + it * BLK;
        colbuf[p] = NEGMAXU;
        const float* s = dbase + (size_t)(pchunk * PCHUNK + p) * 3;
        float x = s[0], y = s[1], z = s[2];
        short hx = f2bf(x), hy = f2bf(y), hz = f2bf(z);
        short lx = f2bf(x - bf2f(hx));
        short ly = f2bf(y - bf2f(hy));
        short lz = f2bf(z - bf2f(hz));
        float w = -0.5f * (x * x + y * y + z * z);
        short wh = f2bf(w);
        short wl = f2bf(w - bf2f(wh));
        unsigned uhx = (unsigned short)hx, uhy = (unsigned short)hy, uhz = (unsigned short)hz;
        unsigned ulx = (unsigned short)lx, uly = (unsigned short)ly, ulz = (unsigned short)lz;
        // half0 k0-7: [phx phy phz phx phy phz plx ply]
        ptsB[p] = make_uint4(uhx | (uhy << 16), uhz | (uhx << 16),
                             uhy | (uhz << 16), ulx | (uly << 16));
        // half1 k8-15: [plz plx ply plz wh wl 1 1]
        ptsB[PCHUNK + p] = make_uint4(
            ulz | (ulx << 16), uly | (ulz << 16),
            (unsigned)(unsigned short)wh | ((unsigned)(unsigned short)wl << 16),
            ((unsigned)ONEBF) | (((unsigned)ONEBF) << 16));
    }

    // ---- A fragments: QA row groups of 32 per wave (p1 queries) ----
    sh8 afrag[QA];
    #pragma unroll
    for (int qa = 0; qa < QA; ++qa) {
        int q = qt * QPB + wave * QPW + qa * 32 + col;
        const float* s = qbase + (size_t)q * 3;
        float x = s[0], y = s[1], z = s[2];
        short hx = f2bf(x), hy = f2bf(y), hz = f2bf(z);
        short lx = f2bf(x - bf2f(hx));
        short ly = f2bf(y - bf2f(hy));
        short lz = f2bf(z - bf2f(hz));
        float w = -0.5f * (x * x + y * y + z * z);
        short nh = f2bf(w);
        short nl = f2bf(w - bf2f(nh));
        // half0 k0-7: [qhx qhy qhz qlx qly qlz qhx qhy]
        // half1 k8-15:[qhz qlx qly qlz  1   1  qnh qnl]
        afrag[qa][0] = half ? hz : hx;
        afrag[qa][1] = half ? lx : hy;
        afrag[qa][2] = half ? ly : hz;
        afrag[qa][3] = half ? lz : lx;
        afrag[qa][4] = half ? (short)ONEBF : ly;
        afrag[qa][5] = half ? (short)ONEBF : lz;
        afrag[qa][6] = half ? nh : hx;
        afrag[qa][7] = half ? nl : hy;
    }
    __syncthreads();

    f32x16 zc;
    f32x16 runmax0, runmax1;
    #pragma unroll
    for (int i = 0; i < 16; ++i) {
        zc[i] = 0.f;
        runmax0[i] = -FLT_MAX;
        runmax1[i] = -FLT_MAX;
    }

    const uint4* bbase = ptsB + half * PCHUNK + col;

    // ---- 32 tiles of 32 cols, 2 tiles/iter ----
    #pragma unroll 2
    for (int t = 0; t < PCHUNK / 32; t += 2) {
        sh8 b0 = *(const sh8*)(bbase + t * 32);
        sh8 b1 = *(const sh8*)(bbase + (t + 1) * 32);
        f32x16 a00 = __builtin_amdgcn_mfma_f32_32x32x16_bf16(afrag[0], b0, zc, 0, 0, 0);
        f32x16 a10 = __builtin_amdgcn_mfma_f32_32x32x16_bf16(afrag[1], b0, zc, 0, 0, 0);
        f32x16 a01 = __builtin_amdgcn_mfma_f32_32x32x16_bf16(afrag[0], b1, zc, 0, 0, 0);
        f32x16 a11 = __builtin_amdgcn_mfma_f32_32x32x16_bf16(afrag[1], b1, zc, 0, 0, 0);
        // row path: running max per row group (v_max3)
        runmax0 = __builtin_elementwise_max(runmax0,
                   __builtin_elementwise_max(a00, a01));
        runmax1 = __builtin_elementwise_max(runmax1,
                   __builtin_elementwise_max(a10, a11));
        // col path: joint 32-elem max3 tree per tile, cross-half, LDS atomic
        float m0 = tree_max32(a00, a10);
        float m1 = tree_max32(a01, a11);
        m0 = fmaxf(m0, __shfl_xor(m0, 32, 64));
        m1 = fmaxf(m1, __shfl_xor(m1, 32, 64));
        atomicMin(&colbuf[t * 32 + col], __float_as_uint(m0));
        atomicMin(&colbuf[(t + 1) * 32 + col], __float_as_uint(m1));
    }

    // ---- row epilogue: shfl-reduce over 32 col-lanes -> part1 ----
    int row0 = batch * NPTS + qt * QPB + wave * QPW;
    float* prow = part1 + (size_t)pchunk * NROW + row0;
    {
        f32x16 rm = runmax0;
        #pragma unroll
        for (int step = 1; step <= 16; step <<= 1) {
            f32x16 o;
            #pragma unroll
            for (int i = 0; i < 16; ++i) o[i] = __shfl_xor(rm[i], step, 64);
            rm = __builtin_elementwise_max(rm, o);
        }
        if (col == 0) {
            #pragma unroll
            for (int reg = 0; reg < 16; ++reg) {
                int r = (reg & 3) + 8 * (reg >> 2) + 4 * half;
                prow[r] = fmaxf(-2.f * rm[reg], 0.f);
            }
        }
        rm = runmax1;
        #pragma unroll
        for (int step = 1; step <= 16; step <<= 1) {
            f32x16 o;
            #pragma unroll
            for (int i = 0; i < 16; ++i) o[i] = __shfl_xor(rm[i], step, 64);
            rm = __builtin_elementwise_max(rm, o);
        }
        if (col == 0) {
            #pragma unroll
            for (int reg = 0; reg < 16; ++reg) {
                int r = (reg & 3) + 8 * (reg >> 2) + 4 * half;
                prow[32 + r] = fmaxf(-2.f * rm[reg], 0.f);
            }
        }
    }

    // ---- col epilogue: colbuf -> part2 ----
    __syncthreads();
    float* pcol = part2 + (size_t)qt * NROW + batch * NPTS + pchunk * PCHUNK;
    #pragma unroll
    for (int it = 0; it < PCHUNK / BLK; ++it) {
        int c = tid + it * BLK;
        float s = __uint_as_float(colbuf[c]);
        pcol[c] = fmaxf(-2.f * s, 0.f);
    }
}

// Stage 2 (fused): blocks [0, NROW/BLK) reduce part1 (8 parts);
// blocks [NROW/BLK, 2*NROW/BLK) reduce part2 (32 parts).
__global__ __launch_bounds__(BLK) void min_sum_fused_kernel(
    const float* __restrict__ part1, const float* __restrict__ part2,
    float* __restrict__ out, float scale)
{
    int half2 = (blockIdx.x >= NROW / BLK);
    const float* part = half2 ? part2 : part1;
    int nparts = half2 ? QTILES : PCH;
    int qid = (blockIdx.x - (half2 ? NROW / BLK : 0)) * BLK + threadIdx.x;
    float v = FLT_MAX;
    for (int m = 0; m < nparts; ++m)
        v = fminf(v, part[(size_t)m * NROW + qid]);
    for (int off = 32; off > 0; off >>= 1) v += __shfl_down(v, off, 64);
    __shared__ float wsum[BLK / 64];
    int lane = threadIdx.x & 63, wid = threadIdx.x >> 6;
    if (lane == 0) wsum[wid] = v;
    __syncthreads();
    if (threadIdx.x == 0) {
        float t = 0.f;
        for (int w = 0; w < BLK / 64; ++w) t += wsum[w];
        atomicAdd(out, t * scale);
    }
}

// ---- fallback path (ws too small): fp32 VALU + atomicMin ----
typedef float v2f __attribute__((ext_vector_type(2)));
typedef float v4f __attribute__((ext_vector_type(4)));
#define FQPT   8
#define FNCH   32
#define FCHUNK (NPTS / FNCH)
#define TOTQ  (2 * BATCH * NPTS)

__global__ __launch_bounds__(BLK) void init_kernel(unsigned* mins, float* out, int n) {
    int i = blockIdx.x * BLK + threadIdx.x;
    if (i < n) mins[i] = 0x7F7FFFFFu;
    if (i == 0) out[0] = 0.f;
}

__global__ __launch_bounds__(BLK) void cd_chunk_atomic_kernel(
    const float* __restrict__ p1, const float* __restrict__ p2,
    unsigned* __restrict__ mins)
{
    __shared__ v4f pts[FCHUNK];
    int bid    = blockIdx.x;
    int mchunk = bid & (FNCH - 1);
    int qt     = (bid >> 5) & 3;
    int batch  = (bid >> 7) & (BATCH - 1);
    int dir    = bid >> 9;
    const float* qbase = (dir == 0 ? p1 : p2) + (size_t)batch * NPTS * 3;
    const float* dbase = (dir == 0 ? p2 : p1) + (size_t)batch * NPTS * 3;
    int tid = threadIdx.x;
    if (tid < FCHUNK / 4) {
        int t4 = tid * 4;
        const float* s = dbase + (size_t)(mchunk * FCHUNK + t4) * 3;
        float4 f0 = *(const float4*)(s);
        float4 f1 = *(const float4*)(s + 4);
        float4 f2 = *(const float4*)(s + 8);
        float x0 = f0.x, y0 = f0.y, z0 = f0.z;
        float x1 = f0.w, y1 = f1.x, z1 = f1.y;
        float x2 = f1.z, y2 = f1.w, z2 = f2.x;
        float x3 = f2.y, y3 = f2.z, z3 = f2.w;
        float w0 = -0.5f * (x0*x0 + y0*y0 + z0*z0);
        float w1 = -0.5f * (x1*x1 + y1*y1 + z1*z1);
        float w2 = -0.5f * (x2*x2 + y2*y2 + z2*z2);
        float w3 = -0.5f * (x3*x3 + y3*y3 + z3*z3);
        pts[4*tid + 0] = (v4f){x0, x1, y0, y1};
        pts[4*tid + 1] = (v4f){z0, z1, w0, w1};
        pts[4*tid + 2] = (v4f){x2, x3, y2, y3};
        pts[4*tid + 3] = (v4f){z2, z3, w2, w3};
    }
    v2f qx2[FQPT], qy2[FQPT], qz2[FQPT];
    float qn[FQPT];
    #pragma unroll
    for (int k = 0; k < FQPT; ++k) {
        int q = qt * (BLK * FQPT) + k * BLK + tid;
        const float* s = qbase + (size_t)q * 3;
        float qx = s[0], qy = s[1], qz = s[2];
        qx2[k] = (v2f){qx, qx}; qy2[k] = (v2f){qy, qy}; qz2[k] = (v2f){qz, qz};
        qn[k] = qx * qx + qy * qy + qz * qz;
    }
    __syncthreads();
    v2f acc0[FQPT], acc1[FQPT];
    #pragma unroll
    for (int k = 0; k < FQPT; ++k) {
        acc0[k] = (v2f){-FLT_MAX, -FLT_MAX};
        acc1[k] = (v2f){-FLT_MAX, -FLT_MAX};
    }
    #pragma unroll 2
    for (int m = 0; m < FCHUNK / 2; m += 2) {
        v4f u0 = pts[2*m + 0], v0 = pts[2*m + 1];
        v4f u1 = pts[2*m + 2], v1 = pts[2*m + 3];
        v2f X0 = __builtin_shufflevector(u0, u0, 0, 1);
        v2f Y0 = __builtin_shufflevector(u0, u0, 2, 3);
        v2f Z0 = __builtin_shufflevector(v0, v0, 0, 1);
        v2f W0 = __builtin_shufflevector(v0, v0, 2, 3);
        v2f X1 = __builtin_shufflevector(u1, u1, 0, 1);
        v2f Y1 = __builtin_shufflevector(u1, u1, 2, 3);
        v2f Z1 = __builtin_shufflevector(v1, v1, 0, 1);
        v2f W1 = __builtin_shufflevector(v1, v1, 2, 3);
        #pragma unroll
        for (int k = 0; k < FQPT; ++k) {
            v2f s0 = __builtin_elementwise_fma(qz2[k], Z0,
                      __builtin_elementwise_fma(qy2[k], Y0,
                       __builtin_elementwise_fma(qx2[k], X0, W0)));
            acc0[k] = __builtin_elementwise_max(acc0[k], s0);
            v2f s1 = __builtin_elementwise_fma(qz2[k], Z1,
                      __builtin_elementwise_fma(qy2[k], Y1,
                       __builtin_elementwise_fma(qx2[k], X1, W1)));
            acc1[k] = __builtin_elementwise_max(acc1[k], s1);
        }
    }
    unsigned qid = (unsigned)(dir * (BATCH * NPTS) + batch * NPTS + qt * (BLK * FQPT) + tid);
    #pragma unroll
    for (int k = 0; k < FQPT; ++k) {
        float mx = fmaxf(fmaxf(acc0[k].x, acc0[k].y), fmaxf(acc1[k].x, acc1[k].y));
        float d = fmaxf(qn[k] - 2.f * mx, 0.f);
        atomicMin(&mins[qid + k * BLK], __float_as_uint(d));
    }
}

__global__ __launch_bounds__(BLK) void sum_kernel(
    const unsigned* __restrict__ mins, float* __restrict__ out, int n, float scale)
{
    int i = blockIdx.x * BLK + threadIdx.x;
    int stride = gridDim.x * BLK;
    float v = 0.f;
    for (int idx = i; idx < n; idx += stride) v += __uint_as_float(mins[idx]);
    for (int off = 32; off > 0; off >>= 1) v += __shfl_down(v, off, 64);
    __shared__ float wsum[BLK / 64];
    int lane = threadIdx.x & 63, wid = threadIdx.x >> 6;
    if (lane == 0) wsum[wid] = v;
    __syncthreads();
    if (threadIdx.x == 0) {
        float t = 0.f;
        for (int w = 0; w < BLK / 64; ++w) t += wsum[w];
        atomicAdd(out, t * scale);
    }
}

extern "C" void kernel_launch(void* const* d_in, const int* in_sizes, int n_in,
                              void* d_out, int out_size, void* d_ws, size_t ws_size,
                              hipStream_t stream) {
    const float* p1 = (const float*)d_in[0];
    const float* p2 = (const float*)d_in[1];
    float* out = (float*)d_out;

    if (ws_size >= WS_NEED) {
        float* part1 = (float*)d_ws;                       // PCH x NROW (1 MB)
        float* part2 = part1 + (size_t)PCH * NROW;         // QTILES x NROW (4 MB)
        zero_out_kernel<<<1, 1, 0, stream>>>(out);
        cd_mfma_kernel<<<GRID, BLK, 0, stream>>>(p1, p2, part1, part2);
        min_sum_fused_kernel<<<2 * NROW / BLK, BLK, 0, stream>>>(
            part1, part2, out, 1.f / (float)NROW);
    } else {
        unsigned* mins = (unsigned*)d_ws;
        init_kernel<<<TOTQ / BLK, BLK, 0, stream>>>(mins, out, TOTQ);
        cd_chunk_atomic_kernel<<<1024, BLK, 0, stream>>>(p1, p2, mins);
        sum_kernel<<<64, BLK, 0, stream>>>(mins, out, TOTQ, 1.f / (float)(BATCH * NPTS));
    }
}

// Round 15
// 89.898 us; speedup vs baseline: 18.4184x; 1.0174x over previous
//
#include <hip/hip_runtime.h>
#include <float.h>

// Chamfer L2, B=4, N=M=8192 fp32 -> scalar.
// bf16 MFMA, K-packed (K=16), symmetric score s_ij = -0.5 d_ij:
//   row-max -> d1 (p1->p2), col-max -> d2 (p2->p1), one MFMA serves both.
// R15 = R14 (best: 91.5us) + zero_out folded into main kernel (one fewer
// dispatch) + launch_bounds(256,3) for 3 waves/SIMD (~170-reg cap, est ~130).
// R13 LESSON: never variable-index an ext_vector -- scratch alloca thrash.
// C layout (HW-verified): col=lane&31, row=(reg&3)+8*(reg>>2)+4*(lane>>5).

typedef short sh8    __attribute__((ext_vector_type(8)));
typedef float f32x16 __attribute__((ext_vector_type(16)));

#define BLK   256
#define BATCH 4
#define NPTS  8192
#define PCH   8                      // point (col) chunks
#define PCHUNK (NPTS / PCH)          // 1024 points staged (32 KB LDS)
#define QA    2                      // A fragments per wave
#define QPW   (QA * 32)              // 64 rows per wave
#define QPB   (4 * QPW)              // 256 rows per block
#define QTILES (NPTS / QPB)          // 32
#define GRID  (BATCH * QTILES * PCH)      // 1024
#define NROW  (BATCH * NPTS)              // 32768
#define WS_NEED ((size_t)(PCH + QTILES) * NROW * sizeof(float))  // 5.25 MB
#define ONEBF 0x3F80
#define NEGMAXU 0xFF7FFFFFu          // bits of -FLT_MAX

__device__ __forceinline__ short f2bf(float f) {
    unsigned u = __float_as_uint(f);
    unsigned r = (u + 0x7FFFu + ((u >> 16) & 1u)) >> 16;
    return (short)r;
}
__device__ __forceinline__ float bf2f(short h) {
    return __uint_as_float(((unsigned)(unsigned short)h) << 16);
}
// max over two f32x16 (32 values) in max3-friendly groups (~18 instrs)
__device__ __forceinline__ float tree_max32(f32x16 u, f32x16 v) {
    float a0 = fmaxf(fmaxf(u[0], u[1]), u[2]);
    float a1 = fmaxf(fmaxf(u[3], u[4]), u[5]);
    float a2 = fmaxf(fmaxf(u[6], u[7]), u[8]);
    float a3 = fmaxf(fmaxf(u[9], u[10]), u[11]);
    float a4 = fmaxf(fmaxf(u[12], u[13]), u[14]);
    float a5 = fmaxf(fmaxf(u[15], v[0]), v[1]);
    float a6 = fmaxf(fmaxf(v[2], v[3]), v[4]);
    float a7 = fmaxf(fmaxf(v[5], v[6]), v[7]);
    float a8 = fmaxf(fmaxf(v[8], v[9]), v[10]);
    float a9 = fmaxf(fmaxf(v[11], v[12]), v[13]);
    float aA = fmaxf(v[14], v[15]);
    float b0 = fmaxf(fmaxf(a0, a1), a2);
    float b1 = fmaxf(fmaxf(a3, a4), a5);
    float b2 = fmaxf(fmaxf(a6, a7), a8);
    float b3 = fmaxf(a9, aA);
    return fmaxf(fmaxf(b0, b1), fmaxf(b2, b3));
}

__global__ __launch_bounds__(BLK, 3) void cd_mfma_kernel(
    const float* __restrict__ p1, const float* __restrict__ p2,
    float* __restrict__ part1, float* __restrict__ part2,
    float* __restrict__ out)
{
    __shared__ uint4 ptsB[2 * PCHUNK];     // [half][point], 32 KB
    __shared__ unsigned colbuf[PCHUNK];    // col-max bits, 4 KB

    int bid    = blockIdx.x;
    int pchunk = bid & (PCH - 1);
    int qt     = (bid >> 3) & (QTILES - 1);
    int batch  = bid >> 8;

    // zero the output once (this dispatch completes before min_sum runs)
    if (bid == 0 && threadIdx.x == 0) out[0] = 0.f;

    const float* qbase = p1 + (size_t)batch * NPTS * 3;   // rows
    const float* dbase = p2 + (size_t)batch * NPTS * 3;   // cols

    int tid  = threadIdx.x;
    int wave = tid >> 6;
    int lane = tid & 63;
    int col  = lane & 31;
    int half = lane >> 5;

    // ---- stage 1024 p2 points + init colbuf ----
    #pragma unroll
    for (int it = 0; it < PCHUNK / BLK; ++it) {
        int p = tid + it * BLK;
        colbuf[p] = NEGMAXU;
        const float* s = dbase + (size_t)(pchunk * PCHUNK + p) * 3;
        float x = s[0], y = s[1], z = s[2];
        short hx = f2bf(x), hy = f2bf(y), hz = f2bf(z);
        short lx = f2bf(x - bf2f(hx));
        short ly = f2bf(y - bf2f(hy));
        short lz = f2bf(z - bf2f(hz));
        float w = -0.5f * (x * x + y * y + z * z);
        short wh = f2bf(w);
        short wl = f2bf(w - bf2f(wh));
        unsigned uhx = (unsigned short)hx, uhy = (unsigned short)hy, uhz = (unsigned short)hz;
        unsigned ulx = (unsigned short)lx, uly = (unsigned short)ly, ulz = (unsigned short)lz;
        // half0 k0-7: [phx phy phz phx phy phz plx ply]
        ptsB[p] = make_uint4(uhx | (uhy << 16), uhz | (uhx << 16),
                             uhy | (uhz << 16), ulx | (uly << 16));
        // half1 k8-15: [plz plx ply plz wh wl 1 1]
        ptsB[PCHUNK + p] = make_uint4(
            ulz | (ulx << 16), uly | (ulz << 16),
            (unsigned)(unsigned short)wh | ((unsigned)(unsigned short)wl << 16),
            ((unsigned)ONEBF) | (((unsigned)ONEBF) << 16));
    }

    // ---- A fragments: QA row groups of 32 per wave (p1 queries) ----
    sh8 afrag[QA];
    #pragma unroll
    for (int qa = 0; qa < QA; ++qa) {
        int q = qt * QPB + wave * QPW + qa * 32 + col;
        const float* s = qbase + (size_t)q * 3;
        float x = s[0], y = s[1], z = s[2];
        short hx = f2bf(x), hy = f2bf(y), hz = f2bf(z);
        short lx = f2bf(x - bf2f(hx));
        short ly = f2bf(y - bf2f(hy));
        short lz = f2bf(z - bf2f(hz));
        float w = -0.5f * (x * x + y * y + z * z);
        short nh = f2bf(w);
        short nl = f2bf(w - bf2f(nh));
        // half0 k0-7: [qhx qhy qhz qlx qly qlz qhx qhy]
        // half1 k8-15:[qhz qlx qly qlz  1   1  qnh qnl]
        afrag[qa][0] = half ? hz : hx;
        afrag[qa][1] = half ? lx : hy;
        afrag[qa][2] = half ? ly : hz;
        afrag[qa][3] = half ? lz : lx;
        afrag[qa][4] = half ? (short)ONEBF : ly;
        afrag[qa][5] = half ? (short)ONEBF : lz;
        afrag[qa][6] = half ? nh : hx;
        afrag[qa][7] = half ? nl : hy;
    }
    __syncthreads();

    f32x16 zc;
    f32x16 runmax0, runmax1;
    #pragma unroll
    for (int i = 0; i < 16; ++i) {
        zc[i] = 0.f;
        runmax0[i] = -FLT_MAX;
        runmax1[i] = -FLT_MAX;
    }

    const uint4* bbase = ptsB + half * PCHUNK + col;

    // ---- 32 tiles of 32 cols, 2 tiles/iter ----
    #pragma unroll 2
    for (int t = 0; t < PCHUNK / 32; t += 2) {
        sh8 b0 = *(const sh8*)(bbase + t * 32);
        sh8 b1 = *(const sh8*)(bbase + (t + 1) * 32);
        f32x16 a00 = __builtin_amdgcn_mfma_f32_32x32x16_bf16(afrag[0], b0, zc, 0, 0, 0);
        f32x16 a10 = __builtin_amdgcn_mfma_f32_32x32x16_bf16(afrag[1], b0, zc, 0, 0, 0);
        f32x16 a01 = __builtin_amdgcn_mfma_f32_32x32x16_bf16(afrag[0], b1, zc, 0, 0, 0);
        f32x16 a11 = __builtin_amdgcn_mfma_f32_32x32x16_bf16(afrag[1], b1, zc, 0, 0, 0);
        // row path: running max per row group (v_max3)
        runmax0 = __builtin_elementwise_max(runmax0,
                   __builtin_elementwise_max(a00, a01));
        runmax1 = __builtin_elementwise_max(runmax1,
                   __builtin_elementwise_max(a10, a11));
        // col path: joint 32-elem max3 tree per tile, cross-half, LDS atomic
        float m0 = tree_max32(a00, a10);
        float m1 = tree_max32(a01, a11);
        m0 = fmaxf(m0, __shfl_xor(m0, 32, 64));
        m1 = fmaxf(m1, __shfl_xor(m1, 32, 64));
        atomicMin(&colbuf[t * 32 + col], __float_as_uint(m0));
        atomicMin(&colbuf[(t + 1) * 32 + col], __float_as_uint(m1));
    }

    // ---- row epilogue: shfl-reduce over 32 col-lanes -> part1 ----
    int row0 = batch * NPTS + qt * QPB + wave * QPW;
    float* prow = part1 + (size_t)pchunk * NROW + row0;
    {
        f32x16 rm = runmax0;
        #pragma unroll
        for (int step = 1; step <= 16; step <<= 1) {
            f32x16 o;
            #pragma unroll
            for (int i = 0; i < 16; ++i) o[i] = __shfl_xor(rm[i], step, 64);
            rm = __builtin_elementwise_max(rm, o);
        }
        if (col == 0) {
            #pragma unroll
            for (int reg = 0; reg < 16; ++reg) {
                int r = (reg & 3) + 8 * (reg >> 2) + 4 * half;
                prow[r] = fmaxf(-2.f * rm[reg], 0.f);
            }
        }
        rm = runmax1;
        #pragma unroll
        for (int step = 1; step <= 16; step <<= 1) {
            f32x16 o;
            #pragma unroll
            for (int i = 0; i < 16; ++i) o[i] = __shfl_xor(rm[i], step, 64);
            rm = __builtin_elementwise_max(rm, o);
        }
        if (col == 0) {
            #pragma unroll
            for (int reg = 0; reg < 16; ++reg) {
                int r = (reg & 3) + 8 * (reg >> 2) + 4 * half;
                prow[32 + r] = fmaxf(-2.f * rm[reg], 0.f);
            }
        }
    }

    // ---- col epilogue: colbuf -> part2 ----
    __syncthreads();
    float* pcol = part2 + (size_t)qt * NROW + batch * NPTS + pchunk * PCHUNK;
    #pragma unroll
    for (int it = 0; it < PCHUNK / BLK; ++it) {
        int c = tid + it * BLK;
        float s = __uint_as_float(colbuf[c]);
        pcol[c] = fmaxf(-2.f * s, 0.f);
    }
}

// Stage 2 (fused): blocks [0, NROW/BLK) reduce part1 (8 parts);
// blocks [NROW/BLK, 2*NROW/BLK) reduce part2 (32 parts).
__global__ __launch_bounds__(BLK) void min_sum_fused_kernel(
    const float* __restrict__ part1, const float* __restrict__ part2,
    float* __restrict__ out, float scale)
{
    int half2 = (blockIdx.x >= NROW / BLK);
    const float* part = half2 ? part2 : part1;
    int nparts = half2 ? QTILES : PCH;
    int qid = (blockIdx.x - (half2 ? NROW / BLK : 0)) * BLK + threadIdx.x;
    float v = FLT_MAX;
    for (int m = 0; m < nparts; ++m)
        v = fminf(v, part[(size_t)m * NROW + qid]);
    for (int off = 32; off > 0; off >>= 1) v += __shfl_down(v, off, 64);
    __shared__ float wsum[BLK / 64];
    int lane = threadIdx.x & 63, wid = threadIdx.x >> 6;
    if (lane == 0) wsum[wid] = v;
    __syncthreads();
    if (threadIdx.x == 0) {
        float t = 0.f;
        for (int w = 0; w < BLK / 64; ++w) t += wsum[w];
        atomicAdd(out, t * scale);
    }
}

// ---- fallback path (ws too small): fp32 VALU + atomicMin ----
typedef float v2f __attribute__((ext_vector_type(2)));
typedef float v4f __attribute__((ext_vector_type(4)));
#define FQPT   8
#define FNCH   32
#define FCHUNK (NPTS / FNCH)
#define TOTQ  (2 * BATCH * NPTS)

__global__ __launch_bounds__(BLK) void init_kernel(unsigned* mins, float* out, int n) {
    int i = blockIdx.x * BLK + threadIdx.x;
    if (i < n) mins[i] = 0x7F7FFFFFu;
    if (i == 0) out[0] = 0.f;
}

__global__ __launch_bounds__(BLK) void cd_chunk_atomic_kernel(
    const float* __restrict__ p1, const float* __restrict__ p2,
    unsigned* __restrict__ mins)
{
    __shared__ v4f pts[FCHUNK];
    int bid    = blockIdx.x;
    int mchunk = bid & (FNCH - 1);
    int qt     = (bid >> 5) & 3;
    int batch  = (bid >> 7) & (BATCH - 1);
    int dir    = bid >> 9;
    const float* qbase = (dir == 0 ? p1 : p2) + (size_t)batch * NPTS * 3;
    const float* dbase = (dir == 0 ? p2 : p1) + (size_t)batch * NPTS * 3;
    int tid = threadIdx.x;
    if (tid < FCHUNK / 4) {
        int t4 = tid * 4;
        const float* s = dbase + (size_t)(mchunk * FCHUNK + t4) * 3;
        float4 f0 = *(const float4*)(s);
        float4 f1 = *(const float4*)(s + 4);
        float4 f2 = *(const float4*)(s + 8);
        float x0 = f0.x, y0 = f0.y, z0 = f0.z;
        float x1 = f0.w, y1 = f1.x, z1 = f1.y;
        float x2 = f1.z, y2 = f1.w, z2 = f2.x;
        float x3 = f2.y, y3 = f2.z, z3 = f2.w;
        float w0 = -0.5f * (x0*x0 + y0*y0 + z0*z0);
        float w1 = -0.5f * (x1*x1 + y1*y1 + z1*z1);
        float w2 = -0.5f * (x2*x2 + y2*y2 + z2*z2);
        float w3 = -0.5f * (x3*x3 + y3*y3 + z3*z3);
        pts[4*tid + 0] = (v4f){x0, x1, y0, y1};
        pts[4*tid + 1] = (v4f){z0, z1, w0, w1};
        pts[4*tid + 2] = (v4f){x2, x3, y2, y3};
        pts[4*tid + 3] = (v4f){z2, z3, w2, w3};
    }
    v2f qx2[FQPT], qy2[FQPT], qz2[FQPT];
    float qn[FQPT];
    #pragma unroll
    for (int k = 0; k < FQPT; ++k) {
        int q = qt * (BLK * FQPT) + k * BLK + tid;
        const float* s = qbase + (size_t)q * 3;
        float qx = s[0], qy = s[1], qz = s[2];
        qx2[k] = (v2f){qx, qx}; qy2[k] = (v2f){qy, qy}; qz2[k] = (v2f){qz, qz};
        qn[k] = qx * qx + qy * qy + qz * qz;
    }
    __syncthreads();
    v2f acc0[FQPT], acc1[FQPT];
    #pragma unroll
    for (int k = 0; k < FQPT; ++k) {
        acc0[k] = (v2f){-FLT_MAX, -FLT_MAX};
        acc1[k] = (v2f){-FLT_MAX, -FLT_MAX};
    }
    #pragma unroll 2
    for (int m = 0; m < FCHUNK / 2; m += 2) {
        v4f u0 = pts[2*m + 0], v0 = pts[2*m + 1];
        v4f u1 = pts[2*m + 2], v1 = pts[2*m + 3];
        v2f X0 = __builtin_shufflevector(u0, u0, 0, 1);
        v2f Y0 = __builtin_shufflevector(u0, u0, 2, 3);
        v2f Z0 = __builtin_shufflevector(v0, v0, 0, 1);
        v2f W0 = __builtin_shufflevector(v0, v0, 2, 3);
        v2f X1 = __builtin_shufflevector(u1, u1, 0, 1);
        v2f Y1 = __builtin_shufflevector(u1, u1, 2, 3);
        v2f Z1 = __builtin_shufflevector(v1, v1, 0, 1);
        v2f W1 = __builtin_shufflevector(v1, v1, 2, 3);
        #pragma unroll
        for (int k = 0; k < FQPT; ++k) {
            v2f s0 = __builtin_elementwise_fma(qz2[k], Z0,
                      __builtin_elementwise_fma(qy2[k], Y0,
                       __builtin_elementwise_fma(qx2[k], X0, W0)));
            acc0[k] = __builtin_elementwise_max(acc0[k], s0);
            v2f s1 = __builtin_elementwise_fma(qz2[k], Z1,
                      __builtin_elementwise_fma(qy2[k], Y1,
                       __builtin_elementwise_fma(qx2[k], X1, W1)));
            acc1[k] = __builtin_elementwise_max(acc1[k], s1);
        }
    }
    unsigned qid = (unsigned)(dir * (BATCH * NPTS) + batch * NPTS + qt * (BLK * FQPT) + tid);
    #pragma unroll
    for (int k = 0; k < FQPT; ++k) {
        float mx = fmaxf(fmaxf(acc0[k].x, acc0[k].y), fmaxf(acc1[k].x, acc1[k].y));
        float d = fmaxf(qn[k] - 2.f * mx, 0.f);
        atomicMin(&mins[qid + k * BLK], __float_as_uint(d));
    }
}

__global__ __launch_bounds__(BLK) void sum_kernel(
    const unsigned* __restrict__ mins, float* __restrict__ out, int n, float scale)
{
    int i = blockIdx.x * BLK + threadIdx.x;
    int stride = gridDim.x * BLK;
    float v = 0.f;
    for (int idx = i; idx < n; idx += stride) v += __uint_as_float(mins[idx]);
    for (int off = 32; off > 0; off >>= 1) v += __shfl_down(v, off, 64);
    __shared__ float wsum[BLK / 64];
    int lane = threadIdx.x & 63, wid = threadIdx.x >> 6;
    if (lane == 0) wsum[wid] = v;
    __syncthreads();
    if (threadIdx.x == 0) {
        float t = 0.f;
        for (int w = 0; w < BLK / 64; ++w) t += wsum[w];
        atomicAdd(out, t * scale);
    }
}

extern "C" void kernel_launch(void* const* d_in, const int* in_sizes, int n_in,
                              void* d_out, int out_size, void* d_ws, size_t ws_size,
                              hipStream_t stream) {
    const float* p1 = (const float*)d_in[0];
    const float* p2 = (const float*)d_in[1];
    float* out = (float*)d_out;

    if (ws_size >= WS_NEED) {
        float* part1 = (float*)d_ws;                       // PCH x NROW (1 MB)
        float* part2 = part1 + (size_t)PCH * NROW;         // QTILES x NROW (4 MB)
        cd_mfma_kernel<<<GRID, BLK, 0, stream>>>(p1, p2, part1, part2, out);
        min_sum_fused_kernel<<<2 * NROW / BLK, BLK, 0, stream>>>(
            part1, part2, out, 1.f / (float)NROW);
    } else {
        unsigned* mins = (unsigned*)d_ws;
        init_kernel<<<TOTQ / BLK, BLK, 0, stream>>>(mins, out, TOTQ);
        cd_chunk_atomic_kernel<<<1024, BLK, 0, stream>>>(p1, p2, mins);
        sum_kernel<<<64, BLK, 0, stream>>>(mins, out, TOTQ, 1.f / (float)(BATCH * NPTS));
    }
}

// Round 16
// 89.847 us; speedup vs baseline: 18.4289x; 1.0006x over previous
//
#include <hip/hip_runtime.h>
#include <float.h>

// Chamfer L2, B=4, N=M=8192 fp32 -> scalar.
// bf16 MFMA, K-packed (K=16), symmetric score s_ij = -0.5 d_ij:
//   row-max -> d1 (p1->p2), col-max -> d2 (p2->p1), one MFMA serves both.
// R16 = R15 (best: 89.9us) minus redundant cross-half shfl in the col path:
// each half-group atomicMins its OWN 32-row partial (colbuf merges via min;
// previously both halves shfl-combined then issued IDENTICAL atomics).
// R13 LESSON: never variable-index an ext_vector -- scratch alloca thrash.
// C layout (HW-verified): col=lane&31, row=(reg&3)+8*(reg>>2)+4*(lane>>5).

typedef short sh8    __attribute__((ext_vector_type(8)));
typedef float f32x16 __attribute__((ext_vector_type(16)));

#define BLK   256
#define BATCH 4
#define NPTS  8192
#define PCH   8                      // point (col) chunks
#define PCHUNK (NPTS / PCH)          // 1024 points staged (32 KB LDS)
#define QA    2                      // A fragments per wave
#define QPW   (QA * 32)              // 64 rows per wave
#define QPB   (4 * QPW)              // 256 rows per block
#define QTILES (NPTS / QPB)          // 32
#define GRID  (BATCH * QTILES * PCH)      // 1024
#define NROW  (BATCH * NPTS)              // 32768
#define WS_NEED ((size_t)(PCH + QTILES) * NROW * sizeof(float))  // 5.25 MB
#define ONEBF 0x3F80
#define NEGMAXU 0xFF7FFFFFu          // bits of -FLT_MAX

__device__ __forceinline__ short f2bf(float f) {
    unsigned u = __float_as_uint(f);
    unsigned r = (u + 0x7FFFu + ((u >> 16) & 1u)) >> 16;
    return (short)r;
}
__device__ __forceinline__ float bf2f(short h) {
    return __uint_as_float(((unsigned)(unsigned short)h) << 16);
}
// max over two f32x16 (32 values) in max3-friendly groups (~18 instrs)
__device__ __forceinline__ float tree_max32(f32x16 u, f32x16 v) {
    float a0 = fmaxf(fmaxf(u[0], u[1]), u[2]);
    float a1 = fmaxf(fmaxf(u[3], u[4]), u[5]);
    float a2 = fmaxf(fmaxf(u[6], u[7]), u[8]);
    float a3 = fmaxf(fmaxf(u[9], u[10]), u[11]);
    float a4 = fmaxf(fmaxf(u[12], u[13]), u[14]);
    float a5 = fmaxf(fmaxf(u[15], v[0]), v[1]);
    float a6 = fmaxf(fmaxf(v[2], v[3]), v[4]);
    float a7 = fmaxf(fmaxf(v[5], v[6]), v[7]);
    float a8 = fmaxf(fmaxf(v[8], v[9]), v[10]);
    float a9 = fmaxf(fmaxf(v[11], v[12]), v[13]);
    float aA = fmaxf(v[14], v[15]);
    float b0 = fmaxf(fmaxf(a0, a1), a2);
    float b1 = fmaxf(fmaxf(a3, a4), a5);
    float b2 = fmaxf(fmaxf(a6, a7), a8);
    float b3 = fmaxf(a9, aA);
    return fmaxf(fmaxf(b0, b1), fmaxf(b2, b3));
}

__global__ __launch_bounds__(BLK, 3) void cd_mfma_kernel(
    const float* __restrict__ p1, const float* __restrict__ p2,
    float* __restrict__ part1, float* __restrict__ part2,
    float* __restrict__ out)
{
    __shared__ uint4 ptsB[2 * PCHUNK];     // [half][point], 32 KB
    __shared__ unsigned colbuf[PCHUNK];    // col-max bits, 4 KB

    int bid    = blockIdx.x;
    int pchunk = bid & (PCH - 1);
    int qt     = (bid >> 3) & (QTILES - 1);
    int batch  = bid >> 8;

    // zero the output once (this dispatch completes before min_sum runs)
    if (bid == 0 && threadIdx.x == 0) out[0] = 0.f;

    const float* qbase = p1 + (size_t)batch * NPTS * 3;   // rows
    const float* dbase = p2 + (size_t)batch * NPTS * 3;   // cols

    int tid  = threadIdx.x;
    int wave = tid >> 6;
    int lane = tid & 63;
    int col  = lane & 31;
    int half = lane >> 5;

    // ---- stage 1024 p2 points + init colbuf ----
    #pragma unroll
    for (int it = 0; it < PCHUNK / BLK; ++it) {
        int p = tid + it * BLK;
        colbuf[p] = NEGMAXU;
        const float* s = dbase + (size_t)(pchunk * PCHUNK + p) * 3;
        float x = s[0], y = s[1], z = s[2];
        short hx = f2bf(x), hy = f2bf(y), hz = f2bf(z);
        short lx = f2bf(x - bf2f(hx));
        short ly = f2bf(y - bf2f(hy));
        short lz = f2bf(z - bf2f(hz));
        float w = -0.5f * (x * x + y * y + z * z);
        short wh = f2bf(w);
        short wl = f2bf(w - bf2f(wh));
        unsigned uhx = (unsigned short)hx, uhy = (unsigned short)hy, uhz = (unsigned short)hz;
        unsigned ulx = (unsigned short)lx, uly = (unsigned short)ly, ulz = (unsigned short)lz;
        // half0 k0-7: [phx phy phz phx phy phz plx ply]
        ptsB[p] = make_uint4(uhx | (uhy << 16), uhz | (uhx << 16),
                             uhy | (uhz << 16), ulx | (uly << 16));
        // half1 k8-15: [plz plx ply plz wh wl 1 1]
        ptsB[PCHUNK + p] = make_uint4(
            ulz | (ulx << 16), uly | (ulz << 16),
            (unsigned)(unsigned short)wh | ((unsigned)(unsigned short)wl << 16),
            ((unsigned)ONEBF) | (((unsigned)ONEBF) << 16));
    }

    // ---- A fragments: QA row groups of 32 per wave (p1 queries) ----
    sh8 afrag[QA];
    #pragma unroll
    for (int qa = 0; qa < QA; ++qa) {
        int q = qt * QPB + wave * QPW + qa * 32 + col;
        const float* s = qbase + (size_t)q * 3;
        float x = s[0], y = s[1], z = s[2];
        short hx = f2bf(x), hy = f2bf(y), hz = f2bf(z);
        short lx = f2bf(x - bf2f(hx));
        short ly = f2bf(y - bf2f(hy));
        short lz = f2bf(z - bf2f(hz));
        float w = -0.5f * (x * x + y * y + z * z);
        short nh = f2bf(w);
        short nl = f2bf(w - bf2f(nh));
        // half0 k0-7: [qhx qhy qhz qlx qly qlz qhx qhy]
        // half1 k8-15:[qhz qlx qly qlz  1   1  qnh qnl]
        afrag[qa][0] = half ? hz : hx;
        afrag[qa][1] = half ? lx : hy;
        afrag[qa][2] = half ? ly : hz;
        afrag[qa][3] = half ? lz : lx;
        afrag[qa][4] = half ? (short)ONEBF : ly;
        afrag[qa][5] = half ? (short)ONEBF : lz;
        afrag[qa][6] = half ? nh : hx;
        afrag[qa][7] = half ? nl : hy;
    }
    __syncthreads();

    f32x16 zc;
    f32x16 runmax0, runmax1;
    #pragma unroll
    for (int i = 0; i < 16; ++i) {
        zc[i] = 0.f;
        runmax0[i] = -FLT_MAX;
        runmax1[i] = -FLT_MAX;
    }

    const uint4* bbase = ptsB + half * PCHUNK + col;

    // ---- 32 tiles of 32 cols, 2 tiles/iter ----
    #pragma unroll 2
    for (int t = 0; t < PCHUNK / 32; t += 2) {
        sh8 b0 = *(const sh8*)(bbase + t * 32);
        sh8 b1 = *(const sh8*)(bbase + (t + 1) * 32);
        f32x16 a00 = __builtin_amdgcn_mfma_f32_32x32x16_bf16(afrag[0], b0, zc, 0, 0, 0);
        f32x16 a10 = __builtin_amdgcn_mfma_f32_32x32x16_bf16(afrag[1], b0, zc, 0, 0, 0);
        f32x16 a01 = __builtin_amdgcn_mfma_f32_32x32x16_bf16(afrag[0], b1, zc, 0, 0, 0);
        f32x16 a11 = __builtin_amdgcn_mfma_f32_32x32x16_bf16(afrag[1], b1, zc, 0, 0, 0);
        // row path: running max per row group (v_max3)
        runmax0 = __builtin_elementwise_max(runmax0,
                   __builtin_elementwise_max(a00, a01));
        runmax1 = __builtin_elementwise_max(runmax1,
                   __builtin_elementwise_max(a10, a11));
        // col path: per-tile joint tree over this half's 32 rows; each half
        // atomicMins its OWN partial (colbuf merges across halves via min).
        float m0 = tree_max32(a00, a10);
        float m1 = tree_max32(a01, a11);
        atomicMin(&colbuf[t * 32 + col], __float_as_uint(m0));
        atomicMin(&colbuf[(t + 1) * 32 + col], __float_as_uint(m1));
    }

    // ---- row epilogue: shfl-reduce over 32 col-lanes -> part1 ----
    int row0 = batch * NPTS + qt * QPB + wave * QPW;
    float* prow = part1 + (size_t)pchunk * NROW + row0;
    {
        f32x16 rm = runmax0;
        #pragma unroll
        for (int step = 1; step <= 16; step <<= 1) {
            f32x16 o;
            #pragma unroll
            for (int i = 0; i < 16; ++i) o[i] = __shfl_xor(rm[i], step, 64);
            rm = __builtin_elementwise_max(rm, o);
        }
        if (col == 0) {
            #pragma unroll
            for (int reg = 0; reg < 16; ++reg) {
                int r = (reg & 3) + 8 * (reg >> 2) + 4 * half;
                prow[r] = fmaxf(-2.f * rm[reg], 0.f);
            }
        }
        rm = runmax1;
        #pragma unroll
        for (int step = 1; step <= 16; step <<= 1) {
            f32x16 o;
            #pragma unroll
            for (int i = 0; i < 16; ++i) o[i] = __shfl_xor(rm[i], step, 64);
            rm = __builtin_elementwise_max(rm, o);
        }
        if (col == 0) {
            #pragma unroll
            for (int reg = 0; reg < 16; ++reg) {
                int r = (reg & 3) + 8 * (reg >> 2) + 4 * half;
                prow[32 + r] = fmaxf(-2.f * rm[reg], 0.f);
            }
        }
    }

    // ---- col epilogue: colbuf -> part2 ----
    __syncthreads();
    float* pcol = part2 + (size_t)qt * NROW + batch * NPTS + pchunk * PCHUNK;
    #pragma unroll
    for (int it = 0; it < PCHUNK / BLK; ++it) {
        int c = tid + it * BLK;
        float s = __uint_as_float(colbuf[c]);
        pcol[c] = fmaxf(-2.f * s, 0.f);
    }
}

// Stage 2 (fused): blocks [0, NROW/BLK) reduce part1 (8 parts);
// blocks [NROW/BLK, 2*NROW/BLK) reduce part2 (32 parts).
__global__ __launch_bounds__(BLK) void min_sum_fused_kernel(
    const float* __restrict__ part1, const float* __restrict__ part2,
    float* __restrict__ out, float scale)
{
    int half2 = (blockIdx.x >= NROW / BLK);
    const float* part = half2 ? part2 : part1;
    int nparts = half2 ? QTILES : PCH;
    int qid = (blockIdx.x - (half2 ? NROW / BLK : 0)) * BLK + threadIdx.x;
    float v = FLT_MAX;
    for (int m = 0; m < nparts; ++m)
        v = fminf(v, part[(size_t)m * NROW + qid]);
    for (int off = 32; off > 0; off >>= 1) v += __shfl_down(v, off, 64);
    __shared__ float wsum[BLK / 64];
    int lane = threadIdx.x & 63, wid = threadIdx.x >> 6;
    if (lane == 0) wsum[wid] = v;
    __syncthreads();
    if (threadIdx.x == 0) {
        float t = 0.f;
        for (int w = 0; w < BLK / 64; ++w) t += wsum[w];
        atomicAdd(out, t * scale);
    }
}

// ---- fallback path (ws too small): fp32 VALU + atomicMin ----
typedef float v2f __attribute__((ext_vector_type(2)));
typedef float v4f __attribute__((ext_vector_type(4)));
#define FQPT   8
#define FNCH   32
#define FCHUNK (NPTS / FNCH)
#define TOTQ  (2 * BATCH * NPTS)

__global__ __launch_bounds__(BLK) void init_kernel(unsigned* mins, float* out, int n) {
    int i = blockIdx.x * BLK + threadIdx.x;
    if (i < n) mins[i] = 0x7F7FFFFFu;
    if (i == 0) out[0] = 0.f;
}

__global__ __launch_bounds__(BLK) void cd_chunk_atomic_kernel(
    const float* __restrict__ p1, const float* __restrict__ p2,
    unsigned* __restrict__ mins)
{
    __shared__ v4f pts[FCHUNK];
    int bid    = blockIdx.x;
    int mchunk = bid & (FNCH - 1);
    int qt     = (bid >> 5) & 3;
    int batch  = (bid >> 7) & (BATCH - 1);
    int dir    = bid >> 9;
    const float* qbase = (dir == 0 ? p1 : p2) + (size_t)batch * NPTS * 3;
    const float* dbase = (dir == 0 ? p2 : p1) + (size_t)batch * NPTS * 3;
    int tid = threadIdx.x;
    if (tid < FCHUNK / 4) {
        int t4 = tid * 4;
        const float* s = dbase + (size_t)(mchunk * FCHUNK + t4) * 3;
        float4 f0 = *(const float4*)(s);
        float4 f1 = *(const float4*)(s + 4);
        float4 f2 = *(const float4*)(s + 8);
        float x0 = f0.x, y0 = f0.y, z0 = f0.z;
        float x1 = f0.w, y1 = f1.x, z1 = f1.y;
        float x2 = f1.z, y2 = f1.w, z2 = f2.x;
        float x3 = f2.y, y3 = f2.z, z3 = f2.w;
        float w0 = -0.5f * (x0*x0 + y0*y0 + z0*z0);
        float w1 = -0.5f * (x1*x1 + y1*y1 + z1*z1);
        float w2 = -0.5f * (x2*x2 + y2*y2 + z2*z2);
        float w3 = -0.5f * (x3*x3 + y3*y3 + z3*z3);
        pts[4*tid + 0] = (v4f){x0, x1, y0, y1};
        pts[4*tid + 1] = (v4f){z0, z1, w0, w1};
        pts[4*tid + 2] = (v4f){x2, x3, y2, y3};
        pts[4*tid + 3] = (v4f){z2, z3, w2, w3};
    }
    v2f qx2[FQPT], qy2[FQPT], qz2[FQPT];
    float qn[FQPT];
    #pragma unroll
    for (int k = 0; k < FQPT; ++k) {
        int q = qt * (BLK * FQPT) + k * BLK + tid;
        const float* s = qbase + (size_t)q * 3;
        float qx = s[0], qy = s[1], qz = s[2];
        qx2[k] = (v2f){qx, qx}; qy2[k] = (v2f){qy, qy}; qz2[k] = (v2f){qz, qz};
        qn[k] = qx * qx + qy * qy + qz * qz;
    }
    __syncthreads();
    v2f acc0[FQPT], acc1[FQPT];
    #pragma unroll
    for (int k = 0; k < FQPT; ++k) {
        acc0[k] = (v2f){-FLT_MAX, -FLT_MAX};
        acc1[k] = (v2f){-FLT_MAX, -FLT_MAX};
    }
    #pragma unroll 2
    for (int m = 0; m < FCHUNK / 2; m += 2) {
        v4f u0 = pts[2*m + 0], v0 = pts[2*m + 1];
        v4f u1 = pts[2*m + 2], v1 = pts[2*m + 3];
        v2f X0 = __builtin_shufflevector(u0, u0, 0, 1);
        v2f Y0 = __builtin_shufflevector(u0, u0, 2, 3);
        v2f Z0 = __builtin_shufflevector(v0, v0, 0, 1);
        v2f W0 = __builtin_shufflevector(v0, v0, 2, 3);
        v2f X1 = __builtin_shufflevector(u1, u1, 0, 1);
        v2f Y1 = __builtin_shufflevector(u1, u1, 2, 3);
        v2f Z1 = __builtin_shufflevector(v1, v1, 0, 1);
        v2f W1 = __builtin_shufflevector(v1, v1, 2, 3);
        #pragma unroll
        for (int k = 0; k < FQPT; ++k) {
            v2f s0 = __builtin_elementwise_fma(qz2[k], Z0,
                      __builtin_elementwise_fma(qy2[k], Y0,
                       __builtin_elementwise_fma(qx2[k], X0, W0)));
            acc0[k] = __builtin_elementwise_max(acc0[k], s0);
            v2f s1 = __builtin_elementwise_fma(qz2[k], Z1,
                      __builtin_elementwise_fma(qy2[k], Y1,
                       __builtin_elementwise_fma(qx2[k], X1, W1)));
            acc1[k] = __builtin_elementwise_max(acc1[k], s1);
        }
    }
    unsigned qid = (unsigned)(dir * (BATCH * NPTS) + batch * NPTS + qt * (BLK * FQPT) + tid);
    #pragma unroll
    for (int k = 0; k < FQPT; ++k) {
        float mx = fmaxf(fmaxf(acc0[k].x, acc0[k].y), fmaxf(acc1[k].x, acc1[k].y));
        float d = fmaxf(qn[k] - 2.f * mx, 0.f);
        atomicMin(&mins[qid + k * BLK], __float_as_uint(d));
    }
}

__global__ __launch_bounds__(BLK) void sum_kernel(
    const unsigned* __restrict__ mins, float* __restrict__ out, int n, float scale)
{
    int i = blockIdx.x * BLK + threadIdx.x;
    int stride = gridDim.x * BLK;
    float v = 0.f;
    for (int idx = i; idx < n; idx += stride) v += __uint_as_float(mins[idx]);
    for (int off = 32; off > 0; off >>= 1) v += __shfl_down(v, off, 64);
    __shared__ float wsum[BLK / 64];
    int lane = threadIdx.x & 63, wid = threadIdx.x >> 6;
    if (lane == 0) wsum[wid] = v;
    __syncthreads();
    if (threadIdx.x == 0) {
        float t = 0.f;
        for (int w = 0; w < BLK / 64; ++w) t += wsum[w];
        atomicAdd(out, t * scale);
    }
}

extern "C" void kernel_launch(void* const* d_in, const int* in_sizes, int n_in,
                              void* d_out, int out_size, void* d_ws, size_t ws_size,
                              hipStream_t stream) {
    const float* p1 = (const float*)d_in[0];
    const float* p2 = (const float*)d_in[1];
    float* out = (float*)d_out;

    if (ws_size >= WS_NEED) {
        float* part1 = (float*)d_ws;                       // PCH x NROW (1 MB)
        float* part2 = part1 + (size_t)PCH * NROW;         // QTILES x NROW (4 MB)
        cd_mfma_kernel<<<GRID, BLK, 0, stream>>>(p1, p2, part1, part2, out);
        min_sum_fused_kernel<<<2 * NROW / BLK, BLK, 0, stream>>>(
            part1, part2, out, 1.f / (float)NROW);
    } else {
        unsigned* mins = (unsigned*)d_ws;
        init_kernel<<<TOTQ / BLK, BLK, 0, stream>>>(mins, out, TOTQ);
        cd_chunk_atomic_kernel<<<1024, BLK, 0, stream>>>(p1, p2, mins);
        sum_kernel<<<64, BLK, 0, stream>>>(mins, out, TOTQ, 1.f / (float)(BATCH * NPTS));
    }
}